// Round 2
// baseline (268.255 us; speedup 1.0000x reference)
//
#include <hip/hip_runtime.h>
#include <cmath>

#define NB     8
#define NVERT  14062
#define NV3    42186      // NVERT*3
#define BATCH  256
#define KP     63         // P rows used (bones 1..7, 9 each)
#define KE     55         // E rows
#define KPAD   120        // padded K (2 zero rows)
#define KT     8          // k-tile
#define NSTEP  15         // KPAD/KT
#define VT     32         // vertices per block

// ---------------- Kernel 1: per-batch setup ----------------
__device__ inline void mat4mul(const float* A, const float* B, float* C) {
#pragma unroll
  for (int i = 0; i < 4; i++)
#pragma unroll
    for (int j = 0; j < 4; j++) {
      float s = 0.f;
#pragma unroll
      for (int k = 0; k < 4; k++) s = fmaf(A[i*4+k], B[k*4+j], s);
      C[i*4+j] = s;
    }
}

__global__ void setup_kernel(const float* __restrict__ theta,  // [256][8][3]
                             const float* __restrict__ bsw,    // [256][55]
                             const float* __restrict__ L2P,    // [8][4][4]
                             float* __restrict__ coef_t,       // [120][256]
                             float* __restrict__ mats)         // [256][8][12]
{
  int b = blockIdx.x * blockDim.x + threadIdx.x;
  if (b >= BATCH) return;

  float R[NB][9];
#pragma unroll
  for (int n = 0; n < NB; n++) {
    float rx = theta[(b*NB+n)*3+0];
    float ry = theta[(b*NB+n)*3+1];
    float rz = theta[(b*NB+n)*3+2];
    float ang = sqrtf(rx*rx + ry*ry + rz*rz + 1e-12f);
    float kx = rx/ang, ky = ry/ang, kz = rz/ang;
    float s = sinf(ang), c = cosf(ang);
    float K[9] = {0.f,-kz,ky,  kz,0.f,-kx,  -ky,kx,0.f};
    float K2[9];
#pragma unroll
    for (int i = 0; i < 3; i++)
#pragma unroll
      for (int j = 0; j < 3; j++) {
        float v = 0.f;
#pragma unroll
        for (int k = 0; k < 3; k++) v = fmaf(K[i*3+k], K[k*3+j], v);
        K2[i*3+j] = v;
      }
#pragma unroll
    for (int e = 0; e < 9; e++) {
      int i = e/3, j = e%3;
      R[n][e] = (i==j ? 1.f : 0.f) + s*K[e] + (1.f-c)*K2[e];
    }
  }

  // coef rows 0..62: theta_zero for bones 1..7 (bone 0 row is exactly zero)
#pragma unroll
  for (int n = 1; n < NB; n++)
#pragma unroll
    for (int e = 0; e < 9; e++) {
      int i = e/3, j = e%3;
      coef_t[((n-1)*9+e)*BATCH + b] = R[n][e] - (i==j ? 1.f : 0.f);
    }
  // rows 63..117: bsw
  for (int s2 = 0; s2 < KE; s2++)
    coef_t[(KP+s2)*BATCH + b] = bsw[b*KE + s2];
  coef_t[118*BATCH + b] = 0.f;
  coef_t[119*BATCH + b] = 0.f;

  // FK chain + rest chain + rigid inverse + skin matrices
  float prevPose[16], prevRest[16];
#pragma unroll 1
  for (int n = 0; n < NB; n++) {
    float loc[16] = {R[n][0],R[n][1],R[n][2],0.f,
                     R[n][3],R[n][4],R[n][5],0.f,
                     R[n][6],R[n][7],R[n][8],0.f,
                     0.f,0.f,0.f,1.f};
    float A[16], pose[16], rest[16];
    mat4mul(&L2P[n*16], loc, A);
    if (n == 0) {
#pragma unroll
      for (int q = 0; q < 16; q++) { pose[q] = A[q]; rest[q] = L2P[q]; }
    } else {
      mat4mul(prevPose, A, pose);
      mat4mul(prevRest, &L2P[n*16], rest);
    }
    // rigid inverse of rest: [R^T, -R^T t]
    float w2l[16];
#pragma unroll
    for (int i = 0; i < 3; i++) {
#pragma unroll
      for (int j = 0; j < 3; j++) w2l[i*4+j] = rest[j*4+i];
      w2l[i*4+3] = -(rest[0*4+i]*rest[0*4+3] + rest[1*4+i]*rest[1*4+3] + rest[2*4+i]*rest[2*4+3]);
    }
    w2l[12]=0.f; w2l[13]=0.f; w2l[14]=0.f; w2l[15]=1.f;
    float skin[16];
    mat4mul(pose, w2l, skin);
#pragma unroll
    for (int i = 0; i < 3; i++)
#pragma unroll
      for (int j = 0; j < 4; j++)
        mats[(size_t)b*96 + n*12 + i*4 + j] = skin[i*4+j];
#pragma unroll
    for (int q = 0; q < 16; q++) { prevPose[q] = pose[q]; prevRest[q] = rest[q]; }
  }
}

// ---------------- Kernel 2: fused GEMM + bilinear + LBS ----------------
__global__ __launch_bounds__(256, 2) void fused_kernel(
    const float* __restrict__ P, const float* __restrict__ E,
    const float* __restrict__ coef_t, const float* __restrict__ matsg,
    const float* __restrict__ Wm, const float* __restrict__ T,
    const float* __restrict__ ts, const float* __restrict__ uvgrid,
    const float* __restrict__ Limg, const float* __restrict__ tau,
    const float* __restrict__ alpha, float* __restrict__ out)
{
  __shared__ float dlds[KT][VT*3];    // 8 x 96 = 3 KB
  __shared__ float clds[KT][BATCH];   // 8 x 256 = 8 KB

  int tid = threadIdx.x;
  int vt  = tid & 7;    // owns 4 consecutive vertices: vbase + vt*4 ..
  int bg  = tid >> 3;   // owns batches bg*8 .. bg*8+7
  int vbase = blockIdx.x * VT;
  size_t vbase3 = (size_t)vbase * 3;
  bool full = (vbase + VT) <= NVERT;
  int dr = tid / 24, dq = tid - dr*24;  // D-tile staging coords (tid<192)

  float acc[8][12];
#pragma unroll
  for (int j = 0; j < 8; j++)
#pragma unroll
    for (int x = 0; x < 12; x++) acc[j][x] = 0.f;

  auto loadD = [&](int step, float4& d) {
    if (tid < 192) {
      int c = step*KT + dr;
      const float* src = (c < KP) ? (P + (size_t)(9 + c)*NV3)
                                  : (E + (size_t)((c < KP+KE ? c : KP+KE-1) - KP)*NV3);
      if (full) {
        d = *reinterpret_cast<const float4*>(src + vbase3 + dq*4);
      } else {
        float t0[4];
#pragma unroll
        for (int u2 = 0; u2 < 4; u2++) {
          size_t idx = vbase3 + (size_t)dq*4 + u2;
          if (idx >= NV3) idx = NV3 - 1;
          t0[u2] = src[idx];
        }
        d = make_float4(t0[0], t0[1], t0[2], t0[3]);
      }
    }
  };
  auto loadC = [&](int step, float4& c0r, float4& c1r) {
    int c0 = step*KT;
    c0r = *reinterpret_cast<const float4*>(coef_t + (size_t)(c0 + (tid>>6))*BATCH + (tid&63)*4);
    c1r = *reinterpret_cast<const float4*>(coef_t + (size_t)(c0 + 4 + (tid>>6))*BATCH + (tid&63)*4);
  };
  auto writeLDS = [&](const float4& d, const float4& c0r, const float4& c1r) {
    if (tid < 192) *reinterpret_cast<float4*>(&dlds[0][0] + tid*4) = d;
    *reinterpret_cast<float4*>(&clds[0][0] + tid*4) = c0r;
    *reinterpret_cast<float4*>(&clds[0][0] + (tid+256)*4) = c1r;
  };

  {
    float4 dreg, c0r, c1r;
    loadD(0, dreg); loadC(0, c0r, c1r);
    writeLDS(dreg, c0r, c1r);
  }
  __syncthreads();

  for (int step = 0; step < NSTEP; ++step) {
    float4 dn, cn0, cn1;
    bool more = (step + 1 < NSTEP);
    if (more) { loadD(step+1, dn); loadC(step+1, cn0, cn1); }
#pragma unroll
    for (int k = 0; k < KT; k++) {
      float4 ca = *reinterpret_cast<const float4*>(&clds[k][bg*8]);
      float4 cb = *reinterpret_cast<const float4*>(&clds[k][bg*8+4]);
      float4 d0 = *reinterpret_cast<const float4*>(&dlds[k][vt*12+0]);
      float4 d1 = *reinterpret_cast<const float4*>(&dlds[k][vt*12+4]);
      float4 d2 = *reinterpret_cast<const float4*>(&dlds[k][vt*12+8]);
      float cf[8] = {ca.x,ca.y,ca.z,ca.w, cb.x,cb.y,cb.z,cb.w};
      float dv[12] = {d0.x,d0.y,d0.z,d0.w, d1.x,d1.y,d1.z,d1.w, d2.x,d2.y,d2.z,d2.w};
#pragma unroll
      for (int j = 0; j < 8; j++)
#pragma unroll
        for (int x = 0; x < 12; x++)
          acc[j][x] = fmaf(cf[j], dv[x], acc[j][x]);
    }
    if (more) {
      __syncthreads();
      writeLDS(dn, cn0, cn1);
      __syncthreads();
    }
  }

  // ---------------- fused epilogue ----------------
  int v0 = vbase + vt*4;
  float ta8[8], al8[8];
#pragma unroll
  for (int j = 0; j < 8; j++) {
    int b = bg*8 + j;
    ta8[j] = tau[b] * 2.f;
    al8[j] = alpha[b];
  }

#pragma unroll
  for (int uh = 0; uh < 2; uh++) {
    float W8[2][NB], Tv[2][3], sv[2][3], wx2[2], gyb2[2];
    int x02[2], x12[2];
    bool val[2];
#pragma unroll
    for (int uu = 0; uu < 2; uu++) {
      int v = v0 + uh*2 + uu;
      val[uu] = (v < NVERT);
      if (val[uu]) {
#pragma unroll
        for (int n = 0; n < NB; n++) W8[uu][n] = Wm[(size_t)n*NVERT + v];
#pragma unroll
        for (int c = 0; c < 3; c++) { Tv[uu][c] = T[v*3+c]; sv[uu][c] = ts[v*3+c]; }
        float u0 = uvgrid[v*2+0], u1 = uvgrid[v*2+1];
        float gx = u0*2.f - 1.f;
        float xc = fminf(fmaxf((gx+1.f)*0.5f*255.f, 0.f), 255.f);
        float xf = floorf(xc);
        x02[uu] = (int)xf; x12[uu] = min(x02[uu]+1, 255);
        wx2[uu] = xc - xf;
        gyb2[uu] = u1*2.f - 1.f;
      } else {
#pragma unroll
        for (int n = 0; n < NB; n++) W8[uu][n] = 0.f;
#pragma unroll
        for (int c = 0; c < 3; c++) { Tv[uu][c] = 0.f; sv[uu][c] = 0.f; }
        wx2[uu] = 0.f; gyb2[uu] = 0.f; x02[uu] = 0; x12[uu] = 0;
      }
    }

#pragma unroll
    for (int j = 0; j < 8; j++) {
      int b = bg*8 + j;
      float xv[2][3];
#pragma unroll
      for (int uu = 0; uu < 2; uu++) {
        float gy = gyb2[uu] + ta8[j];
        float yc = fminf(fmaxf((gy+1.f)*0.5f*255.f, 0.f), 255.f);
        float yf = floorf(yc);
        int y0i = (int)yf;
        int y1i = min(y0i+1, 255);
        float wy = yc - yf;
        float wx = wx2[uu];
        float v00 = Limg[y0i*256 + x02[uu]], v01 = Limg[y0i*256 + x12[uu]];
        float v10 = Limg[y1i*256 + x02[uu]], v11 = Limg[y1i*256 + x12[uu]];
        float dist = (v00*(1.f-wx) + v01*wx)*(1.f-wy) + (v10*(1.f-wx) + v11*wx)*wy;
        float da = dist * al8[j];
        int xo = uh*6 + uu*3;
        xv[uu][0] = acc[j][xo+0] + Tv[uu][0] + da*sv[uu][0];
        xv[uu][1] = acc[j][xo+1] + Tv[uu][1] + da*sv[uu][1];
        xv[uu][2] = acc[j][xo+2] + Tv[uu][2] + da*sv[uu][2];
      }
      float o[2][3];
#pragma unroll
      for (int i = 0; i < 3; i++) {
        float c00=0.f,c01=0.f,c02=0.f,c03=0.f;
        float c10=0.f,c11=0.f,c12=0.f,c13=0.f;
#pragma unroll
        for (int n = 0; n < NB; n++) {
          float4 m = *reinterpret_cast<const float4*>(matsg + (size_t)b*96 + n*12 + i*4);
          float wa = W8[0][n], wb = W8[1][n];
          c00 = fmaf(wa, m.x, c00); c01 = fmaf(wa, m.y, c01);
          c02 = fmaf(wa, m.z, c02); c03 = fmaf(wa, m.w, c03);
          c10 = fmaf(wb, m.x, c10); c11 = fmaf(wb, m.y, c11);
          c12 = fmaf(wb, m.z, c12); c13 = fmaf(wb, m.w, c13);
        }
        o[0][i] = fmaf(c00, xv[0][0], fmaf(c01, xv[0][1], fmaf(c02, xv[0][2], c03)));
        o[1][i] = fmaf(c10, xv[1][0], fmaf(c11, xv[1][1], fmaf(c12, xv[1][2], c13)));
      }
      size_t obase = (size_t)b*NV3 + (size_t)(v0 + uh*2)*3;
      if (val[0] && val[1]) {
        float2* dst = reinterpret_cast<float2*>(out + obase);
        dst[0] = make_float2(o[0][0], o[0][1]);
        dst[1] = make_float2(o[0][2], o[1][0]);
        dst[2] = make_float2(o[1][1], o[1][2]);
      } else {
        if (val[0]) { out[obase+0]=o[0][0]; out[obase+1]=o[0][1]; out[obase+2]=o[0][2]; }
        if (val[1]) { out[obase+3]=o[1][0]; out[obase+4]=o[1][1]; out[obase+5]=o[1][2]; }
      }
    }
  }
}

// ---------------- launcher ----------------
extern "C" void kernel_launch(void* const* d_in, const int* in_sizes, int n_in,
                              void* d_out, int out_size, void* d_ws, size_t ws_size,
                              hipStream_t stream)
{
  const float* theta  = (const float*)d_in[0];
  const float* tau    = (const float*)d_in[1];
  const float* alpha  = (const float*)d_in[2];
  const float* bsw    = (const float*)d_in[3];
  const float* Wm     = (const float*)d_in[4];
  const float* T      = (const float*)d_in[5];
  const float* P      = (const float*)d_in[6];
  const float* L      = (const float*)d_in[7];
  const float* ts     = (const float*)d_in[8];
  const float* L2P    = (const float*)d_in[9];
  const float* E      = (const float*)d_in[10];
  const float* uvgrid = (const float*)d_in[11];
  float* out = (float*)d_out;

  float* coef_t = (float*)d_ws;                    // 120*256 floats
  float* mats   = coef_t + (size_t)KPAD * BATCH;   // 256*96 floats

  setup_kernel<<<dim3(4), dim3(64), 0, stream>>>(theta, bsw, L2P, coef_t, mats);
  fused_kernel<<<dim3((NVERT + VT - 1) / VT), dim3(256), 0, stream>>>(
      P, E, coef_t, mats, Wm, T, ts, uvgrid, L, tau, alpha, out);
}

// Round 4
// 264.263 us; speedup vs baseline: 1.0151x; 1.0151x over previous
//
#include <hip/hip_runtime.h>
#include <cmath>

#define NB     8
#define NVERT  14062
#define NV3    42186      // NVERT*3
#define BATCH  256
#define BH     128        // batches per block
#define KP     63         // P rows used (bones 1..7, 9 each)
#define KE     55         // E rows
#define KPAD   120        // padded K (2 zero rows)
#define KT     8          // k-tile
#define NSTEP  15         // KPAD/KT
#define VT     32         // vertices per block
#define TSTRIDE 100       // transpose-LDS row stride (floats)

// ---------------- Kernel 1: per-batch setup ----------------
__device__ inline void mat4mul(const float* A, const float* B, float* C) {
#pragma unroll
  for (int i = 0; i < 4; i++)
#pragma unroll
    for (int j = 0; j < 4; j++) {
      float s = 0.f;
#pragma unroll
      for (int k = 0; k < 4; k++) s = fmaf(A[i*4+k], B[k*4+j], s);
      C[i*4+j] = s;
    }
}

__global__ void setup_kernel(const float* __restrict__ theta,  // [256][8][3]
                             const float* __restrict__ bsw,    // [256][55]
                             const float* __restrict__ L2P,    // [8][4][4]
                             float* __restrict__ coef_t,       // [120][256]
                             float* __restrict__ mats)         // [256][8][12]
{
  int b = blockIdx.x * blockDim.x + threadIdx.x;
  if (b >= BATCH) return;

  float R[NB][9];
#pragma unroll
  for (int n = 0; n < NB; n++) {
    float rx = theta[(b*NB+n)*3+0];
    float ry = theta[(b*NB+n)*3+1];
    float rz = theta[(b*NB+n)*3+2];
    float ang = sqrtf(rx*rx + ry*ry + rz*rz + 1e-12f);
    float kx = rx/ang, ky = ry/ang, kz = rz/ang;
    float s = sinf(ang), c = cosf(ang);
    float K[9] = {0.f,-kz,ky,  kz,0.f,-kx,  -ky,kx,0.f};
    float K2[9];
#pragma unroll
    for (int i = 0; i < 3; i++)
#pragma unroll
      for (int j = 0; j < 3; j++) {
        float v = 0.f;
#pragma unroll
        for (int k = 0; k < 3; k++) v = fmaf(K[i*3+k], K[k*3+j], v);
        K2[i*3+j] = v;
      }
#pragma unroll
    for (int e = 0; e < 9; e++) {
      int i = e/3, j = e%3;
      R[n][e] = (i==j ? 1.f : 0.f) + s*K[e] + (1.f-c)*K2[e];
    }
  }

  // coef rows 0..62: theta_zero for bones 1..7 (bone 0 row is exactly zero)
#pragma unroll
  for (int n = 1; n < NB; n++)
#pragma unroll
    for (int e = 0; e < 9; e++) {
      int i = e/3, j = e%3;
      coef_t[((n-1)*9+e)*BATCH + b] = R[n][e] - (i==j ? 1.f : 0.f);
    }
  // rows 63..117: bsw
  for (int s2 = 0; s2 < KE; s2++)
    coef_t[(KP+s2)*BATCH + b] = bsw[b*KE + s2];
  coef_t[118*BATCH + b] = 0.f;
  coef_t[119*BATCH + b] = 0.f;

  // FK chain + rest chain + rigid inverse + skin matrices
  float prevPose[16], prevRest[16];
#pragma unroll 1
  for (int n = 0; n < NB; n++) {
    float loc[16] = {R[n][0],R[n][1],R[n][2],0.f,
                     R[n][3],R[n][4],R[n][5],0.f,
                     R[n][6],R[n][7],R[n][8],0.f,
                     0.f,0.f,0.f,1.f};
    float A[16], pose[16], rest[16];
    mat4mul(&L2P[n*16], loc, A);
    if (n == 0) {
#pragma unroll
      for (int q = 0; q < 16; q++) { pose[q] = A[q]; rest[q] = L2P[q]; }
    } else {
      mat4mul(prevPose, A, pose);
      mat4mul(prevRest, &L2P[n*16], rest);
    }
    float w2l[16];
#pragma unroll
    for (int i = 0; i < 3; i++) {
#pragma unroll
      for (int j = 0; j < 3; j++) w2l[i*4+j] = rest[j*4+i];
      w2l[i*4+3] = -(rest[0*4+i]*rest[0*4+3] + rest[1*4+i]*rest[1*4+3] + rest[2*4+i]*rest[2*4+3]);
    }
    w2l[12]=0.f; w2l[13]=0.f; w2l[14]=0.f; w2l[15]=1.f;
    float skin[16];
    mat4mul(pose, w2l, skin);
#pragma unroll
    for (int i = 0; i < 3; i++)
#pragma unroll
      for (int j = 0; j < 4; j++)
        mats[(size_t)b*96 + n*12 + i*4 + j] = skin[i*4+j];
#pragma unroll
    for (int q = 0; q < 16; q++) { prevPose[q] = pose[q]; prevRest[q] = rest[q]; }
  }
}

// ---------------- Kernel 2: fused GEMM + bilinear + LBS (coalesced out) ----
__global__ __launch_bounds__(256) void fused_kernel(
    const float* __restrict__ P, const float* __restrict__ E,
    const float* __restrict__ coef_t, const float* __restrict__ matsg,
    const float* __restrict__ Wm, const float* __restrict__ T,
    const float* __restrict__ ts, const float* __restrict__ uvgrid,
    const float* __restrict__ Limg, const float* __restrict__ tau,
    const float* __restrict__ alpha, float* __restrict__ out)
{
  // smem layout: during GEMM: dlds [KT][96] (768 f) + clds [KT][BH] (1024 f)
  // after GEMM:  tlds [BH][TSTRIDE] (12800 f = 51.2 KB)
  __shared__ float smem[BH * TSTRIDE];
  float* dlds = smem;              // [KT][96]
  float* clds = smem + KT*96;      // [KT][BH]

  int tid = threadIdx.x;
  int vt  = tid & 7;    // 4 consecutive vertices: vbase + vt*4 + {0..3}
  int bq  = tid >> 3;   // 4 consecutive batches: bhalf*BH + bq*4 + {0..3}
  int bhalf = blockIdx.x;          // 0 or 1
  int vbase = blockIdx.y * VT;
  size_t vbase3 = (size_t)vbase * 3;
  bool full = (vbase + VT) <= NVERT;
  int dr = tid / 24, dq = tid - dr*24;  // D staging coords (tid<192)

  float acc[4][12];
#pragma unroll
  for (int j = 0; j < 4; j++)
#pragma unroll
    for (int x = 0; x < 12; x++) acc[j][x] = 0.f;

  auto loadD = [&](int step, float4& d) {
    if (tid < 192) {
      int c = step*KT + dr;
      const float* src = (c < KP) ? (P + (size_t)(9 + c)*NV3)
                                  : (E + (size_t)((c < KP+KE ? c : KP+KE-1) - KP)*NV3);
      if (full) {
        d = *reinterpret_cast<const float4*>(src + vbase3 + dq*4);
      } else {
        float t0[4];
#pragma unroll
        for (int u2 = 0; u2 < 4; u2++) {
          size_t idx = vbase3 + (size_t)dq*4 + u2;
          if (idx >= NV3) idx = NV3 - 1;
          t0[u2] = src[idx];
        }
        d = make_float4(t0[0], t0[1], t0[2], t0[3]);
      }
    }
  };
  auto loadC = [&](int step, float4& cr) {
    int c0 = step*KT;
    cr = *reinterpret_cast<const float4*>(
        coef_t + (size_t)(c0 + (tid>>5))*BATCH + bhalf*BH + (tid&31)*4);
  };
  auto writeLDS = [&](const float4& d, const float4& cr) {
    if (tid < 192) reinterpret_cast<float4*>(dlds)[tid] = d;
    reinterpret_cast<float4*>(clds)[tid] = cr;
  };

  {
    float4 dreg, creg;
    loadD(0, dreg); loadC(0, creg);
    writeLDS(dreg, creg);
  }
  __syncthreads();

  for (int step = 0; step < NSTEP; ++step) {
    float4 dn, cn;
    bool more = (step + 1 < NSTEP);
    if (more) { loadD(step+1, dn); loadC(step+1, cn); }
#pragma unroll
    for (int k = 0; k < KT; k++) {
      float4 cf4 = *reinterpret_cast<const float4*>(&clds[k*BH + bq*4]);
      float4 d0 = *reinterpret_cast<const float4*>(&dlds[k*96 + vt*12 + 0]);
      float4 d1 = *reinterpret_cast<const float4*>(&dlds[k*96 + vt*12 + 4]);
      float4 d2 = *reinterpret_cast<const float4*>(&dlds[k*96 + vt*12 + 8]);
      float cf[4] = {cf4.x, cf4.y, cf4.z, cf4.w};
      float dv[12] = {d0.x,d0.y,d0.z,d0.w, d1.x,d1.y,d1.z,d1.w, d2.x,d2.y,d2.z,d2.w};
#pragma unroll
      for (int j = 0; j < 4; j++)
#pragma unroll
        for (int x = 0; x < 12; x++)
          acc[j][x] = fmaf(cf[j], dv[x], acc[j][x]);
    }
    if (more) {
      __syncthreads();
      writeLDS(dn, cn);
      __syncthreads();
    }
  }
  __syncthreads();   // all GEMM LDS reads done before smem reuse as tlds

  // ---------------- fused epilogue ----------------
  int v0 = vbase + vt*4;
  // per-vertex data (clamped loads for the boundary tile; garbage not stored)
  float W8[4][NB], Tv[4][3], sv[4][3], wxv[4], gyb[4];
  int x0i[4], x1i[4];
#pragma unroll
  for (int u = 0; u < 4; u++) {
    int vc = v0 + u; if (vc > NVERT-1) vc = NVERT-1;
#pragma unroll
    for (int n = 0; n < NB; n++) W8[u][n] = Wm[(size_t)n*NVERT + vc];
#pragma unroll
    for (int c = 0; c < 3; c++) { Tv[u][c] = T[vc*3+c]; sv[u][c] = ts[vc*3+c]; }
    float u0 = uvgrid[vc*2+0], u1 = uvgrid[vc*2+1];
    float gx = u0*2.f - 1.f;
    float xc = fminf(fmaxf((gx+1.f)*0.5f*255.f, 0.f), 255.f);
    float xf = floorf(xc);
    x0i[u] = (int)xf; x1i[u] = min(x0i[u]+1, 255);
    wxv[u] = xc - xf;
    gyb[u] = u1*2.f - 1.f;
  }

#pragma unroll
  for (int j = 0; j < 4; j++) {
    int b = bhalf*BH + bq*4 + j;
    float ta = tau[b] * 2.f;
    float al = alpha[b];
    float o12[12];
#pragma unroll
    for (int u = 0; u < 4; u++) {
      float gy = gyb[u] + ta;
      float yc = fminf(fmaxf((gy+1.f)*0.5f*255.f, 0.f), 255.f);
      float yf = floorf(yc);
      int y0i = (int)yf;
      int y1i = min(y0i+1, 255);
      float wy = yc - yf;
      float wx = wxv[u];
      float v00 = Limg[y0i*256 + x0i[u]], v01 = Limg[y0i*256 + x1i[u]];
      float v10 = Limg[y1i*256 + x0i[u]], v11 = Limg[y1i*256 + x1i[u]];
      float dist = (v00*(1.f-wx) + v01*wx)*(1.f-wy) + (v10*(1.f-wx) + v11*wx)*wy;
      float da = dist * al;
      float xv0 = acc[j][u*3+0] + Tv[u][0] + da*sv[u][0];
      float xv1 = acc[j][u*3+1] + Tv[u][1] + da*sv[u][1];
      float xv2 = acc[j][u*3+2] + Tv[u][2] + da*sv[u][2];
#pragma unroll
      for (int i = 0; i < 3; i++) {
        float c0=0.f, c1=0.f, c2=0.f, c3=0.f;
#pragma unroll
        for (int n = 0; n < NB; n++) {
          float4 m = *reinterpret_cast<const float4*>(matsg + (size_t)b*96 + n*12 + i*4);
          float w = W8[u][n];
          c0 = fmaf(w, m.x, c0); c1 = fmaf(w, m.y, c1);
          c2 = fmaf(w, m.z, c2); c3 = fmaf(w, m.w, c3);
        }
        o12[u*3+i] = fmaf(c0, xv0, fmaf(c1, xv1, fmaf(c2, xv2, c3)));
      }
    }
    // stage into transpose LDS: row = local batch, cols vt*12..+11
    float* trow = smem + (bq*4 + j) * TSTRIDE + vt*12;
    *reinterpret_cast<float4*>(trow + 0) = make_float4(o12[0], o12[1], o12[2],  o12[3]);
    *reinterpret_cast<float4*>(trow + 4) = make_float4(o12[4], o12[5], o12[6],  o12[7]);
    *reinterpret_cast<float4*>(trow + 8) = make_float4(o12[8], o12[9], o12[10], o12[11]);
  }
  __syncthreads();

  // coalesced write-back: 3072 float4 = 128 batches x 24 float4
#pragma unroll
  for (int i = 0; i < 12; i++) {
    int f = tid + 256*i;
    int row = f / 24, chunk = f - row*24;
    float4 val = *reinterpret_cast<const float4*>(smem + row*TSTRIDE + chunk*4);
    size_t b = (size_t)(bhalf*BH + row);
    size_t col = vbase3 + chunk*4;
    if (full || col + 4 <= NV3) {
      *reinterpret_cast<float4*>(out + b*NV3 + col) = val;
    } else {
      float vv[4] = {val.x, val.y, val.z, val.w};
      for (int u2 = 0; u2 < 4; u2++)
        if (col + u2 < NV3) out[b*NV3 + col + u2] = vv[u2];
    }
  }
}

// ---------------- launcher ----------------
extern "C" void kernel_launch(void* const* d_in, const int* in_sizes, int n_in,
                              void* d_out, int out_size, void* d_ws, size_t ws_size,
                              hipStream_t stream)
{
  const float* theta  = (const float*)d_in[0];
  const float* tau    = (const float*)d_in[1];
  const float* alpha  = (const float*)d_in[2];
  const float* bsw    = (const float*)d_in[3];
  const float* Wm     = (const float*)d_in[4];
  const float* T      = (const float*)d_in[5];
  const float* P      = (const float*)d_in[6];
  const float* L      = (const float*)d_in[7];
  const float* ts     = (const float*)d_in[8];
  const float* L2P    = (const float*)d_in[9];
  const float* E      = (const float*)d_in[10];
  const float* uvgrid = (const float*)d_in[11];
  float* out = (float*)d_out;

  float* coef_t = (float*)d_ws;                    // 120*256 floats
  float* mats   = coef_t + (size_t)KPAD * BATCH;   // 256*96 floats

  setup_kernel<<<dim3(4), dim3(64), 0, stream>>>(theta, bsw, L2P, coef_t, mats);
  fused_kernel<<<dim3(2, (NVERT + VT - 1) / VT), dim3(256), 0, stream>>>(
      P, E, coef_t, mats, Wm, T, ts, uvgrid, L, tau, alpha, out);
}

// Round 5
// 221.610 us; speedup vs baseline: 1.2105x; 1.1925x over previous
//
#include <hip/hip_runtime.h>
#include <cmath>

#define NB     8
#define NVERT  14062
#define NV3    42186      // NVERT*3
#define BATCH  256
#define BB     32         // batches per block
#define NBT    16         // batches per thread (2 waves x 16 = 32)
#define KP     63         // P rows used (bones 1..7, 9 each)
#define KE     55         // E rows
#define KPAD   120        // padded K (2 zero rows)
#define KT     8          // k-tile
#define NSTEP  15         // KPAD/KT
#define VT     64         // vertices per block (= wavefront)

// ---------------- Kernel 1: per-batch setup ----------------
__device__ inline void mat4mul(const float* A, const float* B, float* C) {
#pragma unroll
  for (int i = 0; i < 4; i++)
#pragma unroll
    for (int j = 0; j < 4; j++) {
      float s = 0.f;
#pragma unroll
      for (int k = 0; k < 4; k++) s = fmaf(A[i*4+k], B[k*4+j], s);
      C[i*4+j] = s;
    }
}

__global__ void setup_kernel(const float* __restrict__ theta,  // [256][8][3]
                             const float* __restrict__ bsw,    // [256][55]
                             const float* __restrict__ L2P,    // [8][4][4]
                             float* __restrict__ coef_t,       // [120][256]
                             float* __restrict__ mats)         // [256][8][12]
{
  int b = blockIdx.x * blockDim.x + threadIdx.x;
  if (b >= BATCH) return;

  float R[NB][9];
#pragma unroll
  for (int n = 0; n < NB; n++) {
    float rx = theta[(b*NB+n)*3+0];
    float ry = theta[(b*NB+n)*3+1];
    float rz = theta[(b*NB+n)*3+2];
    float ang = sqrtf(rx*rx + ry*ry + rz*rz + 1e-12f);
    float kx = rx/ang, ky = ry/ang, kz = rz/ang;
    float s = sinf(ang), c = cosf(ang);
    float K[9] = {0.f,-kz,ky,  kz,0.f,-kx,  -ky,kx,0.f};
    float K2[9];
#pragma unroll
    for (int i = 0; i < 3; i++)
#pragma unroll
      for (int j = 0; j < 3; j++) {
        float v = 0.f;
#pragma unroll
        for (int k = 0; k < 3; k++) v = fmaf(K[i*3+k], K[k*3+j], v);
        K2[i*3+j] = v;
      }
#pragma unroll
    for (int e = 0; e < 9; e++) {
      int i = e/3, j = e%3;
      R[n][e] = (i==j ? 1.f : 0.f) + s*K[e] + (1.f-c)*K2[e];
    }
  }

  // coef rows 0..62: theta_zero for bones 1..7 (bone 0 row is exactly zero)
#pragma unroll
  for (int n = 1; n < NB; n++)
#pragma unroll
    for (int e = 0; e < 9; e++) {
      int i = e/3, j = e%3;
      coef_t[((n-1)*9+e)*BATCH + b] = R[n][e] - (i==j ? 1.f : 0.f);
    }
  // rows 63..117: bsw
  for (int s2 = 0; s2 < KE; s2++)
    coef_t[(KP+s2)*BATCH + b] = bsw[b*KE + s2];
  coef_t[118*BATCH + b] = 0.f;
  coef_t[119*BATCH + b] = 0.f;

  // FK chain + rest chain + rigid inverse + skin matrices
  float prevPose[16], prevRest[16];
#pragma unroll 1
  for (int n = 0; n < NB; n++) {
    float loc[16] = {R[n][0],R[n][1],R[n][2],0.f,
                     R[n][3],R[n][4],R[n][5],0.f,
                     R[n][6],R[n][7],R[n][8],0.f,
                     0.f,0.f,0.f,1.f};
    float A[16], pose[16], rest[16];
    mat4mul(&L2P[n*16], loc, A);
    if (n == 0) {
#pragma unroll
      for (int q = 0; q < 16; q++) { pose[q] = A[q]; rest[q] = L2P[q]; }
    } else {
      mat4mul(prevPose, A, pose);
      mat4mul(prevRest, &L2P[n*16], rest);
    }
    float w2l[16];
#pragma unroll
    for (int i = 0; i < 3; i++) {
#pragma unroll
      for (int j = 0; j < 3; j++) w2l[i*4+j] = rest[j*4+i];
      w2l[i*4+3] = -(rest[0*4+i]*rest[0*4+3] + rest[1*4+i]*rest[1*4+3] + rest[2*4+i]*rest[2*4+3]);
    }
    w2l[12]=0.f; w2l[13]=0.f; w2l[14]=0.f; w2l[15]=1.f;
    float skin[16];
    mat4mul(pose, w2l, skin);
#pragma unroll
    for (int i = 0; i < 3; i++)
#pragma unroll
      for (int j = 0; j < 4; j++)
        mats[(size_t)b*96 + n*12 + i*4 + j] = skin[i*4+j];
#pragma unroll
    for (int q = 0; q < 16; q++) { prevPose[q] = pose[q]; prevRest[q] = rest[q]; }
  }
}

// ---------------- Kernel 2: fused GEMM + bilinear + LBS ----------------
// block = 128 threads = 2 waves; lane = vertex (64/block), wave owns 16 batches
__global__ __launch_bounds__(128) void fused_kernel(
    const float* __restrict__ P, const float* __restrict__ E,
    const float* __restrict__ coef_t, const float* __restrict__ matsg,
    const float* __restrict__ Wm, const float* __restrict__ T,
    const float* __restrict__ ts, const float* __restrict__ uvgrid,
    const float* __restrict__ Limg, const float* __restrict__ tau,
    const float* __restrict__ alpha, float* __restrict__ out)
{
  __shared__ float dlds[KT][VT*3];   // 8 x 192 = 6 KB
  __shared__ float clds[KT][BB];     // 8 x 32  = 1 KB
  __shared__ float mlds[BB][96];     // 12 KB  (skin mats for this block's batches)
  __shared__ float ta_s[BB], al_s[BB];

  int tid  = threadIdx.x;
  int lane = tid & 63;
  int wv   = tid >> 6;               // 0..1
  int bbase = blockIdx.x * BB;
  int vbase = blockIdx.y * VT;
  int v = vbase + lane;
  bool vok = v < NVERT;
  int vc = vok ? v : NVERT - 1;
  size_t vbase3 = (size_t)vbase * 3;
  bool full = (vbase + VT) <= NVERT;

  // stage mats (32 x 96 floats = 768 float4, 6 per thread) + tau/alpha
#pragma unroll
  for (int r = 0; r < 6; r++) {
    int q = tid + r*128;
    int bb = q / 24, chunk = q - bb*24;
    float4 m = *reinterpret_cast<const float4*>(matsg + (size_t)(bbase+bb)*96 + chunk*4);
    *reinterpret_cast<float4*>(&mlds[bb][chunk*4]) = m;
  }
  if (tid < BB) { ta_s[tid] = tau[bbase+tid]; al_s[tid] = alpha[bbase+tid]; }

  auto loadD = [&](int step, float4 d[3]) {
    int c0 = step * KT;
#pragma unroll
    for (int r = 0; r < 3; r++) {
      int q = tid + r*128;                 // 0..383 (float4 index)
      int row = q / 48, posq = q - row*48;
      int c = c0 + row;
      const float* src = (c < KP) ? (P + (size_t)(9 + c)*NV3)
                                  : (E + (size_t)((c < KP+KE ? c : KP+KE-1) - KP)*NV3);
      if (full) {
        d[r] = *reinterpret_cast<const float4*>(src + vbase3 + posq*4);
      } else {
        float t0[4];
#pragma unroll
        for (int u = 0; u < 4; u++) {
          size_t idx = vbase3 + (size_t)posq*4 + u;
          if (idx >= NV3) idx = NV3 - 1;
          t0[u] = src[idx];
        }
        d[r] = make_float4(t0[0], t0[1], t0[2], t0[3]);
      }
    }
  };
  auto loadC = [&](int step, float4& c4) {
    if (tid < 64) {
      int row = tid >> 3, posq = tid & 7;
      c4 = *reinterpret_cast<const float4*>(
          coef_t + (size_t)(step*KT + row)*BATCH + bbase + posq*4);
    }
  };
  auto writeLDS = [&](float4 d[3], const float4& c4) {
#pragma unroll
    for (int r = 0; r < 3; r++)
      reinterpret_cast<float4*>(&dlds[0][0])[tid + r*128] = d[r];
    if (tid < 64) reinterpret_cast<float4*>(&clds[0][0])[tid] = c4;
  };

  float acc[NBT][3];
#pragma unroll
  for (int j = 0; j < NBT; j++) { acc[j][0]=0.f; acc[j][1]=0.f; acc[j][2]=0.f; }

  {
    float4 dpre[3]; float4 cpre;
    loadD(0, dpre); loadC(0, cpre);
    writeLDS(dpre, cpre);
  }
  __syncthreads();

  for (int step = 0; step < NSTEP; ++step) {
    float4 dpre[3]; float4 cpre;
    bool more = (step + 1 < NSTEP);
    if (more) { loadD(step+1, dpre); loadC(step+1, cpre); }
#pragma unroll
    for (int k = 0; k < KT; k++) {
      float d0 = dlds[k][lane*3+0];
      float d1 = dlds[k][lane*3+1];
      float d2 = dlds[k][lane*3+2];
      float4 ca = *reinterpret_cast<const float4*>(&clds[k][wv*NBT+0]);
      float4 cb = *reinterpret_cast<const float4*>(&clds[k][wv*NBT+4]);
      float4 cc = *reinterpret_cast<const float4*>(&clds[k][wv*NBT+8]);
      float4 cd = *reinterpret_cast<const float4*>(&clds[k][wv*NBT+12]);
      float cf[NBT] = {ca.x,ca.y,ca.z,ca.w, cb.x,cb.y,cb.z,cb.w,
                       cc.x,cc.y,cc.z,cc.w, cd.x,cd.y,cd.z,cd.w};
#pragma unroll
      for (int j = 0; j < NBT; j++) {
        acc[j][0] = fmaf(cf[j], d0, acc[j][0]);
        acc[j][1] = fmaf(cf[j], d1, acc[j][1]);
        acc[j][2] = fmaf(cf[j], d2, acc[j][2]);
      }
    }
    if (more) {
      __syncthreads();
      writeLDS(dpre, cpre);
      __syncthreads();
    }
  }

  // ---------------- fused epilogue (per-vertex lane, 16 batches) ----------
  float W8[NB];
#pragma unroll
  for (int n = 0; n < NB; n++) W8[n] = Wm[(size_t)n*NVERT + vc];
  float T0 = T[vc*3+0], T1 = T[vc*3+1], T2 = T[vc*3+2];
  float s0 = ts[vc*3+0], s1 = ts[vc*3+1], s2 = ts[vc*3+2];
  float u0 = uvgrid[vc*2+0], u1 = uvgrid[vc*2+1];

  // grid_sample coords: x = u0*255 (batch-independent), y = (u1+tau)*255
  float xc = fminf(fmaxf(u0*255.f, 0.f), 255.f);
  float xf = floorf(xc);
  int x0i = (int)xf;
  int x1i = min(x0i+1, 255);
  float wx = xc - xf;

#pragma unroll
  for (int j = 0; j < NBT; j++) {
    int bl = wv*NBT + j;               // batch local index
    float yc = fminf(fmaxf((u1 + ta_s[bl])*255.f, 0.f), 255.f);
    float yf = floorf(yc);
    int y0i = (int)yf;
    int y1i = min(y0i+1, 255);
    float wy = yc - yf;
    float v00 = Limg[y0i*256 + x0i], v01 = Limg[y0i*256 + x1i];
    float v10 = Limg[y1i*256 + x0i], v11 = Limg[y1i*256 + x1i];
    float dist = (v00*(1.f-wx) + v01*wx)*(1.f-wy) + (v10*(1.f-wx) + v11*wx)*wy;
    float da = dist * al_s[bl];

    float xv0 = acc[j][0] + T0 + da*s0;
    float xv1 = acc[j][1] + T1 + da*s1;
    float xv2 = acc[j][2] + T2 + da*s2;

    float o[3];
#pragma unroll
    for (int i = 0; i < 3; i++) {
      float c0=0.f, c1=0.f, c2=0.f, c3=0.f;
#pragma unroll
      for (int n = 0; n < NB; n++) {
        float4 m = *reinterpret_cast<const float4*>(&mlds[bl][n*12 + i*4]);
        float w = W8[n];
        c0 = fmaf(w, m.x, c0); c1 = fmaf(w, m.y, c1);
        c2 = fmaf(w, m.z, c2); c3 = fmaf(w, m.w, c3);
      }
      o[i] = fmaf(c0, xv0, fmaf(c1, xv1, fmaf(c2, xv2, c3)));
    }
    if (vok) {
      size_t off = (size_t)(bbase + bl)*NV3 + (size_t)v*3;
      out[off+0] = o[0];
      out[off+1] = o[1];
      out[off+2] = o[2];
    }
  }
}

// ---------------- launcher ----------------
extern "C" void kernel_launch(void* const* d_in, const int* in_sizes, int n_in,
                              void* d_out, int out_size, void* d_ws, size_t ws_size,
                              hipStream_t stream)
{
  const float* theta  = (const float*)d_in[0];
  const float* tau    = (const float*)d_in[1];
  const float* alpha  = (const float*)d_in[2];
  const float* bsw    = (const float*)d_in[3];
  const float* Wm     = (const float*)d_in[4];
  const float* T      = (const float*)d_in[5];
  const float* P      = (const float*)d_in[6];
  const float* L      = (const float*)d_in[7];
  const float* ts     = (const float*)d_in[8];
  const float* L2P    = (const float*)d_in[9];
  const float* E      = (const float*)d_in[10];
  const float* uvgrid = (const float*)d_in[11];
  float* out = (float*)d_out;

  float* coef_t = (float*)d_ws;                    // 120*256 floats
  float* mats   = coef_t + (size_t)KPAD * BATCH;   // 256*96 floats

  setup_kernel<<<dim3(4), dim3(64), 0, stream>>>(theta, bsw, L2P, coef_t, mats);
  fused_kernel<<<dim3(BATCH/BB, (NVERT + VT - 1) / VT), dim3(128), 0, stream>>>(
      P, E, coef_t, mats, Wm, T, ts, uvgrid, L, tau, alpha, out);
}

// Round 6
// 214.427 us; speedup vs baseline: 1.2510x; 1.0335x over previous
//
#include <hip/hip_runtime.h>
#include <cmath>

#define NB     8
#define NVERT  14062
#define NV3    42186      // NVERT*3
#define BATCH  256
#define BBLK   64         // batches per block
#define NBT    16         // batches per wave-thread (4 waves x 16 = 64)
#define KP     63         // P rows used (bones 1..7, 9 each)
#define KE     55         // E rows
#define KTOT   118        // real K (no padding needed)
#define VT     64         // vertices per block (= wavefront)

// ---------------- Kernel 1: per-batch setup ----------------
__device__ inline void mat4mul(const float* A, const float* B, float* C) {
#pragma unroll
  for (int i = 0; i < 4; i++)
#pragma unroll
    for (int j = 0; j < 4; j++) {
      float s = 0.f;
#pragma unroll
      for (int k = 0; k < 4; k++) s = fmaf(A[i*4+k], B[k*4+j], s);
      C[i*4+j] = s;
    }
}

__global__ void setup_kernel(const float* __restrict__ theta,  // [256][8][3]
                             const float* __restrict__ bsw,    // [256][55]
                             const float* __restrict__ L2P,    // [8][4][4]
                             float* __restrict__ coef_t,       // [118][256]
                             float* __restrict__ mats)         // [256][8][12]
{
  int b = blockIdx.x * blockDim.x + threadIdx.x;
  if (b >= BATCH) return;

  float R[NB][9];
#pragma unroll
  for (int n = 0; n < NB; n++) {
    float rx = theta[(b*NB+n)*3+0];
    float ry = theta[(b*NB+n)*3+1];
    float rz = theta[(b*NB+n)*3+2];
    float ang = sqrtf(rx*rx + ry*ry + rz*rz + 1e-12f);
    float kx = rx/ang, ky = ry/ang, kz = rz/ang;
    float s = sinf(ang), c = cosf(ang);
    float K[9] = {0.f,-kz,ky,  kz,0.f,-kx,  -ky,kx,0.f};
    float K2[9];
#pragma unroll
    for (int i = 0; i < 3; i++)
#pragma unroll
      for (int j = 0; j < 3; j++) {
        float v = 0.f;
#pragma unroll
        for (int k = 0; k < 3; k++) v = fmaf(K[i*3+k], K[k*3+j], v);
        K2[i*3+j] = v;
      }
#pragma unroll
    for (int e = 0; e < 9; e++) {
      int i = e/3, j = e%3;
      R[n][e] = (i==j ? 1.f : 0.f) + s*K[e] + (1.f-c)*K2[e];
    }
  }

  // coef rows 0..62: theta_zero for bones 1..7 (bone 0 row is exactly zero)
#pragma unroll
  for (int n = 1; n < NB; n++)
#pragma unroll
    for (int e = 0; e < 9; e++) {
      int i = e/3, j = e%3;
      coef_t[((n-1)*9+e)*BATCH + b] = R[n][e] - (i==j ? 1.f : 0.f);
    }
  // rows 63..117: bsw
  for (int s2 = 0; s2 < KE; s2++)
    coef_t[(KP+s2)*BATCH + b] = bsw[b*KE + s2];

  // FK chain + rest chain + rigid inverse + skin matrices
  float prevPose[16], prevRest[16];
#pragma unroll 1
  for (int n = 0; n < NB; n++) {
    float loc[16] = {R[n][0],R[n][1],R[n][2],0.f,
                     R[n][3],R[n][4],R[n][5],0.f,
                     R[n][6],R[n][7],R[n][8],0.f,
                     0.f,0.f,0.f,1.f};
    float A[16], pose[16], rest[16];
    mat4mul(&L2P[n*16], loc, A);
    if (n == 0) {
#pragma unroll
      for (int q = 0; q < 16; q++) { pose[q] = A[q]; rest[q] = L2P[q]; }
    } else {
      mat4mul(prevPose, A, pose);
      mat4mul(prevRest, &L2P[n*16], rest);
    }
    float w2l[16];
#pragma unroll
    for (int i = 0; i < 3; i++) {
#pragma unroll
      for (int j = 0; j < 3; j++) w2l[i*4+j] = rest[j*4+i];
      w2l[i*4+3] = -(rest[0*4+i]*rest[0*4+3] + rest[1*4+i]*rest[1*4+3] + rest[2*4+i]*rest[2*4+3]);
    }
    w2l[12]=0.f; w2l[13]=0.f; w2l[14]=0.f; w2l[15]=1.f;
    float skin[16];
    mat4mul(pose, w2l, skin);
#pragma unroll
    for (int i = 0; i < 3; i++)
#pragma unroll
      for (int j = 0; j < 4; j++)
        mats[(size_t)b*96 + n*12 + i*4 + j] = skin[i*4+j];
#pragma unroll
    for (int q = 0; q < 16; q++) { prevPose[q] = pose[q]; prevRest[q] = rest[q]; }
  }
}

// ---------------- Kernel 2: fused GEMM + bilinear + LBS (barrier-free) -----
// 256 threads = 4 waves; lane = vertex; wave wv owns batches bbase+wv*16..+15.
// GEMM reads D (P/E rows) global->reg coalesced and coef as wave-uniform
// float4 loads; NO LDS and NO barriers in the 118-row main loop.
__global__ __launch_bounds__(256) void fused_kernel(
    const float* __restrict__ P, const float* __restrict__ E,
    const float* __restrict__ coef_t, const float* __restrict__ matsg,
    const float* __restrict__ Wm, const float* __restrict__ T,
    const float* __restrict__ ts, const float* __restrict__ uvgrid,
    const float* __restrict__ Limg, const float* __restrict__ tau,
    const float* __restrict__ alpha, float* __restrict__ out)
{
  __shared__ float mlds[BBLK][96];   // 24.6 KB skin mats
  __shared__ float ta_s[BBLK], al_s[BBLK];

  int tid  = threadIdx.x;
  int lane = tid & 63;
  int wv   = tid >> 6;               // 0..3
  int bbase = blockIdx.x * BBLK;
  int vbase = blockIdx.y * VT;
  int v = vbase + lane;
  bool vok = v < NVERT;
  int vc = vok ? v : NVERT - 1;
  size_t voff = (size_t)vc * 3;

  // stage mats (64 x 96 floats = 1536 float4, 6 per thread) + tau/alpha
#pragma unroll
  for (int r = 0; r < 6; r++) {
    int q = tid + r*256;
    int bb = q / 24, chunk = q - bb*24;
    *reinterpret_cast<float4*>(&mlds[bb][chunk*4]) =
        *reinterpret_cast<const float4*>(matsg + (size_t)(bbase+bb)*96 + chunk*4);
  }
  if (tid < BBLK) { ta_s[tid] = tau[bbase+tid]; al_s[tid] = alpha[bbase+tid]; }
  __syncthreads();   // the ONLY barrier

  const float* Pb = P + (size_t)9 * NV3;            // row c<63 -> Pb + c*NV3
  const float* cbase = coef_t + bbase + wv*NBT;     // row stride BATCH

  float acc[NBT][3];
#pragma unroll
  for (int j = 0; j < NBT; j++) { acc[j][0]=0.f; acc[j][1]=0.f; acc[j][2]=0.f; }

  // pipeline registers (A = current row, B = next row)
  float dA0,dA1,dA2, dB0,dB1,dB2;
  float4 cA0,cA1,cA2,cA3, cB0,cB1,cB2,cB3;

  // preload row 0 into A
  {
    const float* rp = Pb + voff;   // row 0 is a P row
    dA0 = rp[0]; dA1 = rp[1]; dA2 = rp[2];
    const float* cp = cbase;
    cA0 = *reinterpret_cast<const float4*>(cp+0);
    cA1 = *reinterpret_cast<const float4*>(cp+4);
    cA2 = *reinterpret_cast<const float4*>(cp+8);
    cA3 = *reinterpret_cast<const float4*>(cp+12);
  }

#define FMA_ROW(D0,D1,D2,C0,C1,C2,C3)                                   \
  {                                                                     \
    float cf[NBT] = {C0.x,C0.y,C0.z,C0.w, C1.x,C1.y,C1.z,C1.w,          \
                     C2.x,C2.y,C2.z,C2.w, C3.x,C3.y,C3.z,C3.w};         \
    _Pragma("unroll")                                                   \
    for (int j = 0; j < NBT; j++) {                                     \
      acc[j][0] = fmaf(cf[j], D0, acc[j][0]);                           \
      acc[j][1] = fmaf(cf[j], D1, acc[j][1]);                           \
      acc[j][2] = fmaf(cf[j], D2, acc[j][2]);                           \
    }                                                                   \
  }

#define LOAD_ROW(cn, D0,D1,D2, C0,C1,C2,C3)                             \
  {                                                                     \
    int c_ = (cn) <= (KTOT-1) ? (cn) : (KTOT-1);                        \
    const float* rp = ((c_ < KP) ? (Pb + (size_t)c_*NV3)                \
                                 : (E + (size_t)(c_-KP)*NV3)) + voff;   \
    D0 = rp[0]; D1 = rp[1]; D2 = rp[2];                                 \
    const float* cp = cbase + (size_t)c_*BATCH;                         \
    C0 = *reinterpret_cast<const float4*>(cp+0);                        \
    C1 = *reinterpret_cast<const float4*>(cp+4);                        \
    C2 = *reinterpret_cast<const float4*>(cp+8);                        \
    C3 = *reinterpret_cast<const float4*>(cp+12);                       \
  }

#pragma unroll 1
  for (int c = 0; c < KTOT; c += 2) {
    LOAD_ROW(c+1, dB0,dB1,dB2, cB0,cB1,cB2,cB3);
    FMA_ROW(dA0,dA1,dA2, cA0,cA1,cA2,cA3);
    LOAD_ROW(c+2, dA0,dA1,dA2, cA0,cA1,cA2,cA3);
    FMA_ROW(dB0,dB1,dB2, cB0,cB1,cB2,cB3);
  }

  // ---------------- fused epilogue (per-vertex lane, 16 batches) ----------
  float W8[NB];
#pragma unroll
  for (int n = 0; n < NB; n++) W8[n] = Wm[(size_t)n*NVERT + vc];
  float T0 = T[vc*3+0], T1 = T[vc*3+1], T2 = T[vc*3+2];
  float s0 = ts[vc*3+0], s1 = ts[vc*3+1], s2 = ts[vc*3+2];
  float u0 = uvgrid[vc*2+0], u1 = uvgrid[vc*2+1];

  // grid_sample coords: x = u0*255 (batch-independent), y = (u1+tau)*255
  float xc = fminf(fmaxf(u0*255.f, 0.f), 255.f);
  float xf = floorf(xc);
  int x0i = (int)xf;
  int x1i = min(x0i+1, 255);
  float wx = xc - xf;

#pragma unroll
  for (int j = 0; j < NBT; j++) {
    int bl = wv*NBT + j;               // batch local index
    float yc = fminf(fmaxf((u1 + ta_s[bl])*255.f, 0.f), 255.f);
    float yf = floorf(yc);
    int y0i = (int)yf;
    int y1i = min(y0i+1, 255);
    float wy = yc - yf;
    float v00 = Limg[y0i*256 + x0i], v01 = Limg[y0i*256 + x1i];
    float v10 = Limg[y1i*256 + x0i], v11 = Limg[y1i*256 + x1i];
    float dist = (v00*(1.f-wx) + v01*wx)*(1.f-wy) + (v10*(1.f-wx) + v11*wx)*wy;
    float da = dist * al_s[bl];

    float xv0 = acc[j][0] + T0 + da*s0;
    float xv1 = acc[j][1] + T1 + da*s1;
    float xv2 = acc[j][2] + T2 + da*s2;

    float o[3];
#pragma unroll
    for (int i = 0; i < 3; i++) {
      float c0=0.f, c1=0.f, c2=0.f, c3=0.f;
#pragma unroll
      for (int n = 0; n < NB; n++) {
        float4 m = *reinterpret_cast<const float4*>(&mlds[bl][n*12 + i*4]);
        float w = W8[n];
        c0 = fmaf(w, m.x, c0); c1 = fmaf(w, m.y, c1);
        c2 = fmaf(w, m.z, c2); c3 = fmaf(w, m.w, c3);
      }
      o[i] = fmaf(c0, xv0, fmaf(c1, xv1, fmaf(c2, xv2, c3)));
    }
    if (vok) {
      size_t off = (size_t)(bbase + bl)*NV3 + (size_t)v*3;
      out[off+0] = o[0];
      out[off+1] = o[1];
      out[off+2] = o[2];
    }
  }
}

// ---------------- launcher ----------------
extern "C" void kernel_launch(void* const* d_in, const int* in_sizes, int n_in,
                              void* d_out, int out_size, void* d_ws, size_t ws_size,
                              hipStream_t stream)
{
  const float* theta  = (const float*)d_in[0];
  const float* tau    = (const float*)d_in[1];
  const float* alpha  = (const float*)d_in[2];
  const float* bsw    = (const float*)d_in[3];
  const float* Wm     = (const float*)d_in[4];
  const float* T      = (const float*)d_in[5];
  const float* P      = (const float*)d_in[6];
  const float* L      = (const float*)d_in[7];
  const float* ts     = (const float*)d_in[8];
  const float* L2P    = (const float*)d_in[9];
  const float* E      = (const float*)d_in[10];
  const float* uvgrid = (const float*)d_in[11];
  float* out = (float*)d_out;

  float* coef_t = (float*)d_ws;                    // 118*256 floats
  float* mats   = coef_t + (size_t)KTOT * BATCH;   // 256*96 floats

  setup_kernel<<<dim3(4), dim3(64), 0, stream>>>(theta, bsw, L2P, coef_t, mats);
  fused_kernel<<<dim3(BATCH/BBLK, (NVERT + VT - 1) / VT), dim3(256), 0, stream>>>(
      P, E, coef_t, mats, Wm, T, ts, uvgrid, L, tau, alpha, out);
}